// Round 1
// baseline (2012.857 us; speedup 1.0000x reference)
//
#include <hip/hip_runtime.h>
#include <hip/hip_bf16.h>

typedef __attribute__((ext_vector_type(8))) short short8;
typedef __attribute__((ext_vector_type(4))) float float4v;
typedef __attribute__((ext_vector_type(2))) _Float16 half2_t;

#if __has_builtin(__builtin_amdgcn_fdot2)
#define FDOT2(w, h, acc) __builtin_amdgcn_fdot2((w), (h), (acc), false)
#else
#define FDOT2(w, h, acc) ((acc) + (float)(w).x * (float)(h).x + (float)(w).y * (float)(h).y)
#endif

__device__ __forceinline__ float sigmoidf_(float x) {
  return __fdividef(1.f, 1.f + __expf(-x));
}
__device__ __forceinline__ float tanhf_(float x) {
  float e = __expf(2.f * x);
  return 1.f - __fdividef(2.f, e + 1.f);
}
__device__ __forceinline__ half2_t packh2(float a, float b) {
  half2_t r;
  r.x = (_Float16)a;
  r.y = (_Float16)b;
  return r;
}

// ---------------------------------------------------------------------------
// Kernel A: projected embedding tables.
// out[v][col] = sum_d A[v][d] * w_row(col)[col_off + d]   (col<1024 -> w_ih_f row col,
// col>=1024 -> w_ih_b row col-1024). bf16 MFMA, 64x64 tile per 256-thread WG.
// ---------------------------------------------------------------------------
__global__ __launch_bounds__(256) void proj_gemm(
    const float* __restrict__ A, int rowsA, int Kdim, int col_off,
    const float* __restrict__ wf, const float* __restrict__ wb,
    const float* __restrict__ bf1, const float* __restrict__ bf2,
    const float* __restrict__ bb1, const float* __restrict__ bb2,
    __hip_bfloat16* __restrict__ out, int add_bias) {
  __shared__ __align__(16) __hip_bfloat16 As[64][40];
  __shared__ __align__(16) __hip_bfloat16 Bs[64][40];
  const int tid = threadIdx.x;
  const int m0 = blockIdx.x * 64, n0 = blockIdx.y * 64;
  const int lane = tid & 63, wave = tid >> 6;
  const int quad = lane >> 4, lm = lane & 15;
  float4v acc[4] = {};
  const int ksteps = (Kdim + 31) >> 5;
  const int r = tid >> 2, c0 = (tid & 3) << 3;
  for (int ks = 0; ks < ksteps; ++ks) {
    const int k0 = ks << 5;
#pragma unroll
    for (int e = 0; e < 8; ++e) {
      int kk = k0 + c0 + e;
      float av = (m0 + r < rowsA && kk < Kdim) ? A[(m0 + r) * Kdim + kk] : 0.f;
      As[r][c0 + e] = __float2bfloat16(av);
      int n = n0 + r;
      float bv = 0.f;
      if (kk < Kdim)
        bv = (n < 1024) ? wf[n * 450 + col_off + kk] : wb[(n - 1024) * 450 + col_off + kk];
      Bs[r][c0 + e] = __float2bfloat16(bv);
    }
    __syncthreads();
    short8 af = *(const short8*)(&As[wave * 16 + lm][quad * 8]);
#pragma unroll
    for (int t = 0; t < 4; ++t) {
      short8 bf = *(const short8*)(&Bs[t * 16 + lm][quad * 8]);
      acc[t] = __builtin_amdgcn_mfma_f32_16x16x32_bf16(af, bf, acc[t], 0, 0, 0);
    }
    __syncthreads();
  }
#pragma unroll
  for (int t = 0; t < 4; ++t) {
#pragma unroll
    for (int rr = 0; rr < 4; ++rr) {
      int m = m0 + wave * 16 + quad * 4 + rr;
      int col = n0 + t * 16 + lm;
      if (m < rowsA) {
        float v = acc[t][rr];
        if (add_bias)
          v += (col < 1024) ? (bf1[col] + bf2[col]) : (bb1[col - 1024] + bb2[col - 1024]);
        out[m * 2048 + col] = __float2bfloat16(v);
      }
    }
  }
}

// ---------------------------------------------------------------------------
// Kernel B: BiLSTM recurrence. One WG (512 threads, 8 waves) per (batch, dir)
// chain; w_hh f16 register-resident (116 pairs/row) + LDS (12 pairs/row).
// Thread tid owns gate rows tid and tid+512. v_dot2_f32_f16 inner product.
// ---------------------------------------------------------------------------
__global__ __launch_bounds__(512, 2) void lstm_kernel(
    const float* __restrict__ whh_f, const float* __restrict__ whh_b,
    const int* __restrict__ x, const int* __restrict__ ptags, const int* __restrict__ gtags,
    const __hip_bfloat16* __restrict__ char_proj,
    const __hip_bfloat16* __restrict__ pin_proj,
    const __hip_bfloat16* __restrict__ tag_proj,
    __hip_bfloat16* __restrict__ h_out) {
  __shared__ __align__(16) half2_t wl[1024][12];  // 48 KB
  __shared__ float sf[256];
  __shared__ float so[256];
  __shared__ __align__(16) _Float16 hbuf[256];

  const int tid = threadIdx.x;
  const int chain = blockIdx.x;       // 0..255
  const int dir = chain >> 7;         // 0 fwd, 1 bwd
  const int b = chain & 127;
  const float* __restrict__ whh = dir ? whh_b : whh_f;
  const int r0 = tid;
  const int r1 = tid + 512;

  half2_t wA[116], wB[116];
  {
    const float2* row0 = (const float2*)(whh + r0 * 256);
    const float2* row1 = (const float2*)(whh + r1 * 256);
#pragma unroll
    for (int p = 0; p < 116; ++p) {
      float2 v0 = row0[p];
      float2 v1 = row1[p];
      wA[p] = packh2(v0.x, v0.y);
      wB[p] = packh2(v1.x, v1.y);
    }
#pragma unroll
    for (int p = 0; p < 12; ++p) {
      float2 v0 = row0[116 + p];
      float2 v1 = row1[116 + p];
      wl[r0][p] = packh2(v0.x, v0.y);
      wl[r1][p] = packh2(v1.x, v1.y);
    }
  }
  if (tid < 256) hbuf[tid] = (_Float16)0.f;
  __syncthreads();

  const int col0 = dir * 1024 + r0;
  const int col1 = dir * 1024 + r1;
  float cst = 0.f;
  const uint4* hv = (const uint4*)hbuf;
  const uint4* w0p = (const uint4*)(&wl[r0][0]);
  const uint4* w1p = (const uint4*)(&wl[r1][0]);

  for (int s = 0; s < 512; ++s) {
    const int t = dir ? (511 - s) : s;
    const int ti = b * 512 + t;
    const int xt = x[ti] * 2048;
    const int pt = ptags[ti] * 2048;
    const int gt = gtags[ti] * 2048;
    float pre0 = __bfloat162float(char_proj[xt + col0]) +
                 __bfloat162float(pin_proj[pt + col0]) +
                 __bfloat162float(tag_proj[gt + col0]);
    float pre1 = __bfloat162float(char_proj[xt + col1]) +
                 __bfloat162float(pin_proj[pt + col1]) +
                 __bfloat162float(tag_proj[gt + col1]);
    float a0 = 0.f, a1 = 0.f, d0 = 0.f, d1 = 0.f;
#pragma unroll
    for (int q = 0; q < 29; ++q) {
      uint4 hh = hv[q];
      half2_t h0 = __builtin_bit_cast(half2_t, hh.x);
      half2_t h1 = __builtin_bit_cast(half2_t, hh.y);
      half2_t h2 = __builtin_bit_cast(half2_t, hh.z);
      half2_t h3 = __builtin_bit_cast(half2_t, hh.w);
      a0 = FDOT2(wA[4 * q + 0], h0, a0);
      a1 = FDOT2(wA[4 * q + 1], h1, a1);
      d0 = FDOT2(wB[4 * q + 0], h0, d0);
      d1 = FDOT2(wB[4 * q + 1], h1, d1);
      a0 = FDOT2(wA[4 * q + 2], h2, a0);
      a1 = FDOT2(wA[4 * q + 3], h3, a1);
      d0 = FDOT2(wB[4 * q + 2], h2, d0);
      d1 = FDOT2(wB[4 * q + 3], h3, d1);
    }
#pragma unroll
    for (int j = 0; j < 3; ++j) {
      uint4 hh = hv[29 + j];
      uint4 u0 = w0p[j];
      uint4 u1 = w1p[j];
      a0 = FDOT2(__builtin_bit_cast(half2_t, u0.x), __builtin_bit_cast(half2_t, hh.x), a0);
      a1 = FDOT2(__builtin_bit_cast(half2_t, u0.y), __builtin_bit_cast(half2_t, hh.y), a1);
      d0 = FDOT2(__builtin_bit_cast(half2_t, u1.x), __builtin_bit_cast(half2_t, hh.x), d0);
      d1 = FDOT2(__builtin_bit_cast(half2_t, u1.y), __builtin_bit_cast(half2_t, hh.y), d1);
      a0 = FDOT2(__builtin_bit_cast(half2_t, u0.z), __builtin_bit_cast(half2_t, hh.z), a0);
      a1 = FDOT2(__builtin_bit_cast(half2_t, u0.w), __builtin_bit_cast(half2_t, hh.w), a1);
      d0 = FDOT2(__builtin_bit_cast(half2_t, u1.z), __builtin_bit_cast(half2_t, hh.z), d0);
      d1 = FDOT2(__builtin_bit_cast(half2_t, u1.w), __builtin_bit_cast(half2_t, hh.w), d1);
    }
    const float g0 = pre0 + a0 + a1;  // tid<256: i_j   | tid>=256: f_j
    const float g1 = pre1 + d0 + d1;  // tid<256: g_j   | tid>=256: o_j
    float part = 0.f;
    if (tid < 256) {
      part = sigmoidf_(g0) * tanhf_(g1);
    } else {
      sf[tid - 256] = sigmoidf_(g0);
      so[tid - 256] = sigmoidf_(g1);
    }
    __syncthreads();
    if (tid < 256) {
      cst = sf[tid] * cst + part;
      float hval = so[tid] * tanhf_(cst);
      hbuf[tid] = (_Float16)hval;
      h_out[((size_t)chain * 512 + t) * 256 + tid] = __float2bfloat16(hval);
    }
    __syncthreads();
  }
}

// ---------------------------------------------------------------------------
// Kernel C: emissions GEMM. em[b*512+t][k] = sum_j Hcat[n][j]*w_out[k][j] + b_out[k]
// Hcat: j<256 from dir0, j>=256 from dir1. h layout: [dir][b][t][256] bf16.
// ---------------------------------------------------------------------------
__global__ __launch_bounds__(256) void emis_kernel(
    const __hip_bfloat16* __restrict__ h_glob, const float* __restrict__ w_out,
    const float* __restrict__ b_out, float* __restrict__ em) {
  __shared__ __align__(16) __hip_bfloat16 As[64][40];
  __shared__ __align__(16) __hip_bfloat16 Bs[32][40];
  const int tid = threadIdx.x;
  const int n0 = blockIdx.x * 64;
  const int lane = tid & 63, wave = tid >> 6, quad = lane >> 4, lm = lane & 15;
  float4v acc[2] = {};
  const int r = tid >> 2, c0 = (tid & 3) << 3;
  const int rb = tid >> 3, cb = (tid & 7) << 2;
  for (int ks = 0; ks < 16; ++ks) {
    const int j0 = ks * 32;
    const int dirk = j0 >> 8, jin = j0 & 255;
    const int n = n0 + r, bb = n >> 9, tt = n & 511;
    const uint4* src =
        (const uint4*)(h_glob + ((size_t)(dirk * 128 + bb) * 512 + tt) * 256 + jin + c0);
    *(uint4*)(&As[r][c0]) = *src;
#pragma unroll
    for (int e = 0; e < 4; ++e) {
      float v = (rb < 20) ? w_out[rb * 512 + j0 + cb + e] : 0.f;
      Bs[rb][cb + e] = __float2bfloat16(v);
    }
    __syncthreads();
    short8 af = *(const short8*)(&As[wave * 16 + lm][quad * 8]);
#pragma unroll
    for (int t2 = 0; t2 < 2; ++t2) {
      short8 bf = *(const short8*)(&Bs[t2 * 16 + lm][quad * 8]);
      acc[t2] = __builtin_amdgcn_mfma_f32_16x16x32_bf16(af, bf, acc[t2], 0, 0, 0);
    }
    __syncthreads();
  }
#pragma unroll
  for (int t2 = 0; t2 < 2; ++t2) {
#pragma unroll
    for (int rr = 0; rr < 4; ++rr) {
      int col = t2 * 16 + lm;
      if (col < 20) {
        int n = n0 + wave * 16 + quad * 4 + rr;
        em[(size_t)n * 20 + col] = acc[t2][rr] + b_out[col];
      }
    }
  }
}

// ---------------------------------------------------------------------------
// Kernel D: CRF forward NLL per batch element. 1 wave per b.
// alpha_new[j] = em[t][j] + P + log(sum_i exp(alpha[i]-P) * exp(trans[i][j]))
// exp(trans) precomputed in 20 registers per lane.
// ---------------------------------------------------------------------------
__global__ __launch_bounds__(64) void crf_kernel(
    const float* __restrict__ em, const int* __restrict__ y,
    const float* __restrict__ start_trans, const float* __restrict__ end_trans,
    const float* __restrict__ trans, float* __restrict__ partials) {
  const int b = blockIdx.x;
  const int lane = threadIdx.x;
  const int jj = lane < 20 ? lane : 19;
  const bool act = lane < 20;
  __shared__ float sea[64];
  float ET[20];
#pragma unroll
  for (int i = 0; i < 20; ++i) ET[i] = __expf(trans[i * 20 + jj]);
  float alpha = act ? (start_trans[jj] + em[(size_t)(b * 512) * 20 + jj]) : -1e30f;
  int yprev = y[b * 512];
  float score = start_trans[yprev] + em[(size_t)(b * 512) * 20 + yprev];
  for (int t = 1; t < 512; ++t) {
    float P = alpha;
#pragma unroll
    for (int k = 32; k >= 1; k >>= 1) P = fmaxf(P, __shfl_xor(P, k, 64));
    sea[lane] = __expf(alpha - P);
    __syncthreads();
    float s0 = 0.f, s1 = 0.f;
#pragma unroll
    for (int i = 0; i < 20; i += 2) {
      s0 += sea[i] * ET[i];
      s1 += sea[i + 1] * ET[i + 1];
    }
    const size_t row = (size_t)(b * 512 + t) * 20;
    float em_t = em[row + jj];
    if (act) alpha = P + __logf(s0 + s1) + em_t;
    int yc = y[b * 512 + t];
    score += trans[yprev * 20 + yc] + em[row + yc];
    yprev = yc;
    __syncthreads();
  }
  float v = act ? (alpha + end_trans[jj]) : -1e30f;
  float P = v;
#pragma unroll
  for (int k = 32; k >= 1; k >>= 1) P = fmaxf(P, __shfl_xor(P, k, 64));
  float e2 = __expf(v - P);
#pragma unroll
  for (int k = 32; k >= 1; k >>= 1) e2 += __shfl_xor(e2, k, 64);
  float logZ = P + __logf(e2);
  score += end_trans[y[b * 512 + 511]];
  if (lane == 0) partials[b] = logZ - score;
}

__global__ __launch_bounds__(128) void reduce_kernel(const float* __restrict__ partials,
                                                     float* __restrict__ out) {
  const int tid = threadIdx.x;
  float v = partials[tid];
#pragma unroll
  for (int k = 32; k >= 1; k >>= 1) v += __shfl_xor(v, k, 64);
  __shared__ float tmp[2];
  if ((tid & 63) == 0) tmp[tid >> 6] = v;
  __syncthreads();
  if (tid == 0) out[0] = tmp[0] + tmp[1];
}

// ---------------------------------------------------------------------------
extern "C" void kernel_launch(void* const* d_in, const int* in_sizes, int n_in,
                              void* d_out, int out_size, void* d_ws, size_t ws_size,
                              hipStream_t stream) {
  const int* x = (const int*)d_in[0];
  const int* y = (const int*)d_in[1];
  const int* pre_tags = (const int*)d_in[2];
  const int* pinyin_tags = (const int*)d_in[3];
  // d_in[4] mask: all ones in this problem -- ignored.
  const float* char_emb = (const float*)d_in[5];
  const float* tag_emb = (const float*)d_in[6];
  const float* pinyin_emb = (const float*)d_in[7];
  const float* w_ih_f = (const float*)d_in[8];
  const float* w_hh_f = (const float*)d_in[9];
  const float* b_ih_f = (const float*)d_in[10];
  const float* b_hh_f = (const float*)d_in[11];
  const float* w_ih_b = (const float*)d_in[12];
  const float* w_hh_b = (const float*)d_in[13];
  const float* b_ih_b = (const float*)d_in[14];
  const float* b_hh_b = (const float*)d_in[15];
  const float* w_out = (const float*)d_in[16];
  const float* b_out = (const float*)d_in[17];
  const float* start_trans = (const float*)d_in[18];
  const float* end_trans = (const float*)d_in[19];
  const float* trans = (const float*)d_in[20];

  char* ws = (char*)d_ws;
  __hip_bfloat16* char_proj = (__hip_bfloat16*)(ws);                  // 10002*2048*2 = 40968192
  __hip_bfloat16* pin_proj = (__hip_bfloat16*)(ws + 40968192);        // 500*2048*2  = 2048000
  __hip_bfloat16* tag_proj = (__hip_bfloat16*)(ws + 43016192);        // 20*2048*2   = 81920
  __hip_bfloat16* h_glob = (__hip_bfloat16*)(ws + 43098112);          // 2*128*512*256*2 = 67108864
  float* em = (float*)(ws + 110206976);                               // 65536*20*4 = 5242880
  float* partials = (float*)(ws + 115449856);                         // 128*4

  // A: projected tables (char / pinyin / tag+bias)
  proj_gemm<<<dim3(157, 32), 256, 0, stream>>>(char_emb, 10002, 300, 0, w_ih_f, w_ih_b,
                                               nullptr, nullptr, nullptr, nullptr, char_proj, 0);
  proj_gemm<<<dim3(8, 32), 256, 0, stream>>>(pinyin_emb, 500, 100, 300, w_ih_f, w_ih_b,
                                             nullptr, nullptr, nullptr, nullptr, pin_proj, 0);
  proj_gemm<<<dim3(1, 32), 256, 0, stream>>>(tag_emb, 20, 50, 400, w_ih_f, w_ih_b,
                                             b_ih_f, b_hh_f, b_ih_b, b_hh_b, tag_proj, 1);
  // B: recurrence (256 chains = 128 batch x 2 dirs)
  lstm_kernel<<<256, 512, 0, stream>>>(w_hh_f, w_hh_b, x, pinyin_tags, pre_tags,
                                       char_proj, pin_proj, tag_proj, h_glob);
  // C: emissions
  emis_kernel<<<1024, 256, 0, stream>>>(h_glob, w_out, b_out, em);
  // D: CRF per batch element
  crf_kernel<<<128, 64, 0, stream>>>(em, y, start_trans, end_trans, trans, partials);
  // E: final sum -> d_out[0]
  reduce_kernel<<<1, 128, 0, stream>>>(partials, (float*)d_out);
}

// Round 2
// 1827.164 us; speedup vs baseline: 1.1016x; 1.1016x over previous
//
#include <hip/hip_runtime.h>
#include <hip/hip_bf16.h>

typedef __attribute__((ext_vector_type(8))) short short8;
typedef __attribute__((ext_vector_type(4))) float float4v;
typedef __attribute__((ext_vector_type(2))) _Float16 half2_t;

#if __has_builtin(__builtin_amdgcn_fdot2)
#define FDOT2(w, h, acc) __builtin_amdgcn_fdot2((w), (h), (acc), false)
#else
#define FDOT2(w, h, acc) ((acc) + (float)(w).x * (float)(h).x + (float)(w).y * (float)(h).y)
#endif

__device__ __forceinline__ float sigmoidf_(float x) {
  return __fdividef(1.f, 1.f + __expf(-x));
}
__device__ __forceinline__ float tanhf_(float x) {
  float e = __expf(2.f * x);
  return 1.f - __fdividef(2.f, e + 1.f);
}
__device__ __forceinline__ half2_t packh2(float a, float b) {
  half2_t r;
  r.x = (_Float16)a;
  r.y = (_Float16)b;
  return r;
}
__device__ __forceinline__ float bflo(unsigned int v) {
  return __uint_as_float(v << 16);
}
__device__ __forceinline__ float bfhi(unsigned int v) {
  return __uint_as_float(v & 0xffff0000u);
}

// ---------------------------------------------------------------------------
// Kernel A: projected embedding tables, INTERLEAVED output layout.
// Logical col n in [0,2048): dir=n>>10, r=n&1023, u=r&511, hi=r>>9.
// Stored at out[m*2048 + dir*1024 + u*2 + hi] so lstm thread tid loads its
// two gate-rows (tid, tid+512) as ONE uint.
// Grid (ceil(rowsA/64), 8): m-block 64, n-block 256 (A traffic /4 vs n-block 64).
// ---------------------------------------------------------------------------
__global__ __launch_bounds__(256) void proj_gemm(
    const float* __restrict__ A, int rowsA, int Kdim, int col_off,
    const float* __restrict__ wf, const float* __restrict__ wb,
    const float* __restrict__ bf1, const float* __restrict__ bf2,
    const float* __restrict__ bb1, const float* __restrict__ bb2,
    __hip_bfloat16* __restrict__ out, int add_bias) {
  __shared__ __align__(16) __hip_bfloat16 As[64][40];
  __shared__ __align__(16) __hip_bfloat16 Bs[256][40];
  const int tid = threadIdx.x;
  const int m0 = blockIdx.x * 64, n0 = blockIdx.y * 256;
  const int lane = tid & 63, wave = tid >> 6;
  const int quad = lane >> 4, lm = lane & 15;
  float4v acc[16] = {};
  const int ksteps = (Kdim + 31) >> 5;
  const int r = tid >> 2, c0 = (tid & 3) << 3;
  for (int ks = 0; ks < ksteps; ++ks) {
    const int k0 = ks << 5;
    // A tile 64x32
#pragma unroll
    for (int e = 0; e < 8; ++e) {
      int kk = k0 + c0 + e;
      float av = (m0 + r < rowsA && kk < Kdim) ? A[(m0 + r) * Kdim + kk] : 0.f;
      As[r][c0 + e] = __float2bfloat16(av);
    }
    // B tile 256x32: thread tid owns row n0+tid, float2 granularity (Kdim even)
    {
      int n = n0 + tid;
      const float* __restrict__ wrow =
          (n < 1024) ? (wf + n * 450 + col_off) : (wb + (n - 1024) * 450 + col_off);
#pragma unroll
      for (int e2 = 0; e2 < 16; ++e2) {
        int kk = k0 + e2 * 2;
        float b0 = 0.f, b1 = 0.f;
        if (kk < Kdim) {
          b0 = wrow[kk];
          b1 = wrow[kk + 1];
        }
        Bs[tid][e2 * 2] = __float2bfloat16(b0);
        Bs[tid][e2 * 2 + 1] = __float2bfloat16(b1);
      }
    }
    __syncthreads();
    short8 af = *(const short8*)(&As[wave * 16 + lm][quad * 8]);
#pragma unroll
    for (int t = 0; t < 16; ++t) {
      short8 bf = *(const short8*)(&Bs[t * 16 + lm][quad * 8]);
      acc[t] = __builtin_amdgcn_mfma_f32_16x16x32_bf16(af, bf, acc[t], 0, 0, 0);
    }
    __syncthreads();
  }
#pragma unroll
  for (int t = 0; t < 16; ++t) {
#pragma unroll
    for (int rr = 0; rr < 4; ++rr) {
      int m = m0 + wave * 16 + quad * 4 + rr;
      int col = n0 + t * 16 + lm;  // logical col
      if (m < rowsA) {
        float v = acc[t][rr];
        if (add_bias)
          v += (col < 1024) ? (bf1[col] + bf2[col]) : (bb1[col - 1024] + bb2[col - 1024]);
        int dir = col >> 10, rr2 = col & 1023;
        int u = rr2 & 511, hi = rr2 >> 9;
        out[m * 2048 + dir * 1024 + u * 2 + hi] = __float2bfloat16(v);
      }
    }
  }
}

// ---------------------------------------------------------------------------
// Kernel B: BiLSTM recurrence. 256 WGs (1/CU), 512 threads (8 waves, 2/SIMD).
// Thread tid owns gate rows tid (i|f) and tid+512 (g|o).
// Weights f16: cols 0..191 in VGPRs (96 half2 x 2 rows = 192 regs),
// cols 192..255 in LDS (1024 rows x 32 pairs, padded stride 33 -> 132 KB).
// Indices preloaded to LDS; proj-table gathers prefetched 1 step ahead.
// ---------------------------------------------------------------------------
#define RP 96  // register pairs per row
#define LP 32  // LDS pairs per row
#define WSTRIDE 33

__global__ __launch_bounds__(512, 2) void lstm_kernel(
    const float* __restrict__ whh_f, const float* __restrict__ whh_b,
    const int* __restrict__ x, const int* __restrict__ ptags, const int* __restrict__ gtags,
    const unsigned int* __restrict__ char_proj,
    const unsigned int* __restrict__ pin_proj,
    const unsigned int* __restrict__ tag_proj,
    __hip_bfloat16* __restrict__ h_out) {
  extern __shared__ char smem[];
  half2_t* wl = (half2_t*)smem;                       // 1024*33*4 = 135168
  int* sx = (int*)(smem + 135168);                    // 2048
  int* sp = (int*)(smem + 137216);                    // 2048
  int* sg = (int*)(smem + 139264);                    // 2048
  float* sf = (float*)(smem + 141312);                // 1024
  float* so = (float*)(smem + 142336);                // 1024
  _Float16* hbuf = (_Float16*)(smem + 143360);        // 512 (16B aligned)

  const int tid = threadIdx.x;
  const int chain = blockIdx.x;  // 0..255
  const int dir = chain >> 7;
  const int b = chain & 127;
  const float* __restrict__ whh = dir ? whh_b : whh_f;
  const int r0 = tid;
  const int r1 = tid + 512;

  // indices to LDS
  sx[tid] = x[b * 512 + tid];
  sp[tid] = ptags[b * 512 + tid];
  sg[tid] = gtags[b * 512 + tid];

  // weights: rows r0, r1 (256 f32 each) -> f16 pairs
  half2_t wA[RP], wB[RP];
  {
    const float4* row0 = (const float4*)(whh + r0 * 256);
    const float4* row1 = (const float4*)(whh + r1 * 256);
#pragma unroll
    for (int q = 0; q < RP / 2; ++q) {  // float4 idx 0..47 -> cols 0..191
      float4 v0 = row0[q];
      float4 v1 = row1[q];
      wA[2 * q] = packh2(v0.x, v0.y);
      wA[2 * q + 1] = packh2(v0.z, v0.w);
      wB[2 * q] = packh2(v1.x, v1.y);
      wB[2 * q + 1] = packh2(v1.z, v1.w);
    }
#pragma unroll
    for (int q = 0; q < LP / 2; ++q) {  // float4 idx 48..63 -> cols 192..255
      float4 v0 = row0[RP / 2 + q];
      float4 v1 = row1[RP / 2 + q];
      wl[r0 * WSTRIDE + 2 * q] = packh2(v0.x, v0.y);
      wl[r0 * WSTRIDE + 2 * q + 1] = packh2(v0.z, v0.w);
      wl[r1 * WSTRIDE + 2 * q] = packh2(v1.x, v1.y);
      wl[r1 * WSTRIDE + 2 * q + 1] = packh2(v1.z, v1.w);
    }
  }
  if (tid < 256) hbuf[tid] = (_Float16)0.f;
  __syncthreads();

  const unsigned int goff = (unsigned int)(dir * 512 + tid);
  float cst = 0.f;
  const uint4* hv = (const uint4*)hbuf;
  const half2_t* wl0 = wl + r0 * WSTRIDE;
  const half2_t* wl1 = wl + r1 * WSTRIDE;

  // prefetch step 0
  int t_cur = dir ? 511 : 0;
  unsigned int pc = char_proj[(unsigned int)sx[t_cur] * 1024u + goff];
  unsigned int pp = pin_proj[(unsigned int)sp[t_cur] * 1024u + goff];
  unsigned int pg = tag_proj[(unsigned int)sg[t_cur] * 1024u + goff];

  for (int s = 0; s < 512; ++s) {
    const int t = t_cur;
    const unsigned int cv = pc, pv = pp, gv = pg;
    // issue next prefetch (clamped; redundant load on last iter is harmless)
    const int tn = dir ? (t > 0 ? t - 1 : 0) : (t < 511 ? t + 1 : 511);
    t_cur = tn;
    pc = char_proj[(unsigned int)sx[tn] * 1024u + goff];
    pp = pin_proj[(unsigned int)sp[tn] * 1024u + goff];
    pg = tag_proj[(unsigned int)sg[tn] * 1024u + goff];

    float a0 = 0.f, a1 = 0.f, d0 = 0.f, d1 = 0.f;
    // register-weight cols 0..191 (24 uint4 h-groups x 4 pairs)
#pragma unroll
    for (int q = 0; q < 24; ++q) {
      uint4 hh = hv[q];
      half2_t h0 = __builtin_bit_cast(half2_t, hh.x);
      half2_t h1 = __builtin_bit_cast(half2_t, hh.y);
      half2_t h2 = __builtin_bit_cast(half2_t, hh.z);
      half2_t h3 = __builtin_bit_cast(half2_t, hh.w);
      a0 = FDOT2(wA[4 * q + 0], h0, a0);
      d0 = FDOT2(wB[4 * q + 0], h0, d0);
      a1 = FDOT2(wA[4 * q + 1], h1, a1);
      d1 = FDOT2(wB[4 * q + 1], h1, d1);
      a0 = FDOT2(wA[4 * q + 2], h2, a0);
      d0 = FDOT2(wB[4 * q + 2], h2, d0);
      a1 = FDOT2(wA[4 * q + 3], h3, a1);
      d1 = FDOT2(wB[4 * q + 3], h3, d1);
    }
    // LDS-weight cols 192..255 (8 uint4 h-groups x 4 pairs)
#pragma unroll
    for (int j = 0; j < 8; ++j) {
      uint4 hh = hv[24 + j];
      half2_t h0 = __builtin_bit_cast(half2_t, hh.x);
      half2_t h1 = __builtin_bit_cast(half2_t, hh.y);
      half2_t h2 = __builtin_bit_cast(half2_t, hh.z);
      half2_t h3 = __builtin_bit_cast(half2_t, hh.w);
      a0 = FDOT2(wl0[4 * j + 0], h0, a0);
      d0 = FDOT2(wl1[4 * j + 0], h0, d0);
      a1 = FDOT2(wl0[4 * j + 1], h1, a1);
      d1 = FDOT2(wl1[4 * j + 1], h1, d1);
      a0 = FDOT2(wl0[4 * j + 2], h2, a0);
      d0 = FDOT2(wl1[4 * j + 2], h2, d0);
      a1 = FDOT2(wl0[4 * j + 3], h3, a1);
      d1 = FDOT2(wl1[4 * j + 3], h3, d1);
    }
    const float g0 = bflo(cv) + bflo(pv) + bflo(gv) + a0 + a1;  // i | f
    const float g1 = bfhi(cv) + bfhi(pv) + bfhi(gv) + d0 + d1;  // g | o
    float part = 0.f;
    if (tid < 256) {
      part = sigmoidf_(g0) * tanhf_(g1);
    } else {
      sf[tid - 256] = sigmoidf_(g0);
      so[tid - 256] = sigmoidf_(g1);
    }
    __syncthreads();
    if (tid < 256) {
      cst = sf[tid] * cst + part;
      float hval = so[tid] * tanhf_(cst);
      hbuf[tid] = (_Float16)hval;
      h_out[((size_t)chain * 512 + t) * 256 + tid] = __float2bfloat16(hval);
    }
    __syncthreads();
  }
}

// ---------------------------------------------------------------------------
// Kernel C: emissions GEMM. em[n][k] = sum_j Hcat[n][j]*w_out[k][j] + b_out[k]
// ---------------------------------------------------------------------------
__global__ __launch_bounds__(256) void emis_kernel(
    const __hip_bfloat16* __restrict__ h_glob, const float* __restrict__ w_out,
    const float* __restrict__ b_out, float* __restrict__ em) {
  __shared__ __align__(16) __hip_bfloat16 As[64][40];
  __shared__ __align__(16) __hip_bfloat16 Bs[32][40];
  const int tid = threadIdx.x;
  const int n0 = blockIdx.x * 64;
  const int lane = tid & 63, wave = tid >> 6, quad = lane >> 4, lm = lane & 15;
  float4v acc[2] = {};
  const int r = tid >> 2, c0 = (tid & 3) << 3;
  const int rb = tid >> 3, cb = (tid & 7) << 2;
  for (int ks = 0; ks < 16; ++ks) {
    const int j0 = ks * 32;
    const int dirk = j0 >> 8, jin = j0 & 255;
    const int n = n0 + r, bb = n >> 9, tt = n & 511;
    const uint4* src =
        (const uint4*)(h_glob + ((size_t)(dirk * 128 + bb) * 512 + tt) * 256 + jin + c0);
    *(uint4*)(&As[r][c0]) = *src;
#pragma unroll
    for (int e = 0; e < 4; ++e) {
      float v = (rb < 20) ? w_out[rb * 512 + j0 + cb + e] : 0.f;
      Bs[rb][cb + e] = __float2bfloat16(v);
    }
    __syncthreads();
    short8 af = *(const short8*)(&As[wave * 16 + lm][quad * 8]);
#pragma unroll
    for (int t2 = 0; t2 < 2; ++t2) {
      short8 bf = *(const short8*)(&Bs[t2 * 16 + lm][quad * 8]);
      acc[t2] = __builtin_amdgcn_mfma_f32_16x16x32_bf16(af, bf, acc[t2], 0, 0, 0);
    }
    __syncthreads();
  }
#pragma unroll
  for (int t2 = 0; t2 < 2; ++t2) {
#pragma unroll
    for (int rr = 0; rr < 4; ++rr) {
      int col = t2 * 16 + lm;
      if (col < 20) {
        int n = n0 + wave * 16 + quad * 4 + rr;
        em[(size_t)n * 20 + col] = acc[t2][rr] + b_out[col];
      }
    }
  }
}

// ---------------------------------------------------------------------------
// Kernel D: CRF forward NLL per batch element. 1 wave per b.
// ---------------------------------------------------------------------------
__global__ __launch_bounds__(64) void crf_kernel(
    const float* __restrict__ em, const int* __restrict__ y,
    const float* __restrict__ start_trans, const float* __restrict__ end_trans,
    const float* __restrict__ trans, float* __restrict__ partials) {
  const int b = blockIdx.x;
  const int lane = threadIdx.x;
  const int jj = lane < 20 ? lane : 19;
  const bool act = lane < 20;
  __shared__ float sea[64];
  float ET[20];
#pragma unroll
  for (int i = 0; i < 20; ++i) ET[i] = __expf(trans[i * 20 + jj]);
  float alpha = act ? (start_trans[jj] + em[(size_t)(b * 512) * 20 + jj]) : -1e30f;
  int yprev = y[b * 512];
  float score = start_trans[yprev] + em[(size_t)(b * 512) * 20 + yprev];
  for (int t = 1; t < 512; ++t) {
    float P = alpha;
#pragma unroll
    for (int k = 32; k >= 1; k >>= 1) P = fmaxf(P, __shfl_xor(P, k, 64));
    sea[lane] = __expf(alpha - P);
    __syncthreads();
    float s0 = 0.f, s1 = 0.f;
#pragma unroll
    for (int i = 0; i < 20; i += 2) {
      s0 += sea[i] * ET[i];
      s1 += sea[i + 1] * ET[i + 1];
    }
    const size_t row = (size_t)(b * 512 + t) * 20;
    float em_t = em[row + jj];
    if (act) alpha = P + __logf(s0 + s1) + em_t;
    int yc = y[b * 512 + t];
    score += trans[yprev * 20 + yc] + em[row + yc];
    yprev = yc;
    __syncthreads();
  }
  float v = act ? (alpha + end_trans[jj]) : -1e30f;
  float P = v;
#pragma unroll
  for (int k = 32; k >= 1; k >>= 1) P = fmaxf(P, __shfl_xor(P, k, 64));
  float e2 = __expf(v - P);
#pragma unroll
  for (int k = 32; k >= 1; k >>= 1) e2 += __shfl_xor(e2, k, 64);
  float logZ = P + __logf(e2);
  score += end_trans[y[b * 512 + 511]];
  if (lane == 0) partials[b] = logZ - score;
}

__global__ __launch_bounds__(128) void reduce_kernel(const float* __restrict__ partials,
                                                     float* __restrict__ out) {
  const int tid = threadIdx.x;
  float v = partials[tid];
#pragma unroll
  for (int k = 32; k >= 1; k >>= 1) v += __shfl_xor(v, k, 64);
  __shared__ float tmp[2];
  if ((tid & 63) == 0) tmp[tid >> 6] = v;
  __syncthreads();
  if (tid == 0) out[0] = tmp[0] + tmp[1];
}

// ---------------------------------------------------------------------------
extern "C" void kernel_launch(void* const* d_in, const int* in_sizes, int n_in,
                              void* d_out, int out_size, void* d_ws, size_t ws_size,
                              hipStream_t stream) {
  const int* x = (const int*)d_in[0];
  const int* y = (const int*)d_in[1];
  const int* pre_tags = (const int*)d_in[2];
  const int* pinyin_tags = (const int*)d_in[3];
  const float* char_emb = (const float*)d_in[5];
  const float* tag_emb = (const float*)d_in[6];
  const float* pinyin_emb = (const float*)d_in[7];
  const float* w_ih_f = (const float*)d_in[8];
  const float* w_hh_f = (const float*)d_in[9];
  const float* b_ih_f = (const float*)d_in[10];
  const float* b_hh_f = (const float*)d_in[11];
  const float* w_ih_b = (const float*)d_in[12];
  const float* w_hh_b = (const float*)d_in[13];
  const float* b_ih_b = (const float*)d_in[14];
  const float* b_hh_b = (const float*)d_in[15];
  const float* w_out = (const float*)d_in[16];
  const float* b_out = (const float*)d_in[17];
  const float* start_trans = (const float*)d_in[18];
  const float* end_trans = (const float*)d_in[19];
  const float* trans = (const float*)d_in[20];

  char* ws = (char*)d_ws;
  __hip_bfloat16* char_proj = (__hip_bfloat16*)(ws);            // 10002*2048*2 = 40968192
  __hip_bfloat16* pin_proj = (__hip_bfloat16*)(ws + 40968192);  // 500*2048*2  = 2048000
  __hip_bfloat16* tag_proj = (__hip_bfloat16*)(ws + 43016192);  // 20*2048*2   = 81920
  __hip_bfloat16* h_glob = (__hip_bfloat16*)(ws + 43098112);    // 2*128*512*256*2 = 67108864
  float* em = (float*)(ws + 110206976);                         // 65536*20*4 = 5242880
  float* partials = (float*)(ws + 115449856);                   // 128*4

  proj_gemm<<<dim3(157, 8), 256, 0, stream>>>(char_emb, 10002, 300, 0, w_ih_f, w_ih_b,
                                              nullptr, nullptr, nullptr, nullptr, char_proj, 0);
  proj_gemm<<<dim3(8, 8), 256, 0, stream>>>(pinyin_emb, 500, 100, 300, w_ih_f, w_ih_b,
                                            nullptr, nullptr, nullptr, nullptr, pin_proj, 0);
  proj_gemm<<<dim3(1, 8), 256, 0, stream>>>(tag_emb, 20, 50, 400, w_ih_f, w_ih_b,
                                            b_ih_f, b_hh_f, b_ih_b, b_hh_b, tag_proj, 1);

  const int lstm_lds = 143872;
  hipFuncSetAttribute((const void*)lstm_kernel, hipFuncAttributeMaxDynamicSharedMemorySize,
                      lstm_lds);
  lstm_kernel<<<256, 512, lstm_lds, stream>>>(w_hh_f, w_hh_b, x, pinyin_tags, pre_tags,
                                              (const unsigned int*)char_proj,
                                              (const unsigned int*)pin_proj,
                                              (const unsigned int*)tag_proj, h_glob);

  emis_kernel<<<1024, 256, 0, stream>>>(h_glob, w_out, b_out, em);
  crf_kernel<<<128, 64, 0, stream>>>(em, y, start_trans, end_trans, trans, partials);
  reduce_kernel<<<1, 128, 0, stream>>>(partials, (float*)d_out);
}

// Round 3
// 1636.399 us; speedup vs baseline: 1.2301x; 1.1166x over previous
//
#include <hip/hip_runtime.h>
#include <hip/hip_bf16.h>

typedef __attribute__((ext_vector_type(8))) short short8;
typedef __attribute__((ext_vector_type(4))) float float4v;

#if __has_builtin(__builtin_amdgcn_sdot4)
#define DOT4(a, b, c) __builtin_amdgcn_sdot4((int)(a), (int)(b), (c), false)
#else
__device__ __forceinline__ int dot4_(int a, int b, int c) {
  c += (int)(signed char)(a) * (int)(signed char)(b);
  c += (int)(signed char)(a >> 8) * (int)(signed char)(b >> 8);
  c += (int)(signed char)(a >> 16) * (int)(signed char)(b >> 16);
  c += (a >> 24) * (b >> 24);
  return c;
}
#define DOT4(a, b, c) dot4_((int)(a), (int)(b), (c))
#endif

__device__ __forceinline__ float sigmoidf_(float x) {
  return __fdividef(1.f, 1.f + __expf(-x));
}
__device__ __forceinline__ float tanhf_(float x) {
  float e = __expf(2.f * x);
  return 1.f - __fdividef(2.f, e + 1.f);
}
__device__ __forceinline__ float bflo(unsigned int v) {
  return __uint_as_float(v << 16);
}
__device__ __forceinline__ float bfhi(unsigned int v) {
  return __uint_as_float(v & 0xffff0000u);
}

// quad (4-lane) butterflies via DPP quad_perm (VALU, not DS pipe)
template <int CTRL>
__device__ __forceinline__ int qadd_i(int v) {
  return v + __builtin_amdgcn_update_dpp(0, v, CTRL, 0xF, 0xF, true);
}
template <int CTRL>
__device__ __forceinline__ float qmax_f(float v) {
  int r = __builtin_amdgcn_update_dpp(0, __float_as_int(v), CTRL, 0xF, 0xF, true);
  return fmaxf(v, __int_as_float(r));
}
#define XOR1 0xB1  // quad_perm [1,0,3,2]
#define XOR2 0x4E  // quad_perm [2,3,0,1]

// ---------------------------------------------------------------------------
// Kernel A: projected embedding tables.
// Logical col n in [0,2048): dir=n>>10, r=n&1023, gate=r>>8, u=r&255.
// Stored at out[m*2048 + dir*1024 + u*4 + gate]  ([row][dir][unit][i,f,g,o]).
// ---------------------------------------------------------------------------
__global__ __launch_bounds__(256) void proj_gemm(
    const float* __restrict__ A, int rowsA, int Kdim, int col_off,
    const float* __restrict__ wf, const float* __restrict__ wb,
    const float* __restrict__ bf1, const float* __restrict__ bf2,
    const float* __restrict__ bb1, const float* __restrict__ bb2,
    __hip_bfloat16* __restrict__ out, int add_bias) {
  __shared__ __align__(16) __hip_bfloat16 As[64][40];
  __shared__ __align__(16) __hip_bfloat16 Bs[256][40];
  const int tid = threadIdx.x;
  const int m0 = blockIdx.x * 64, n0 = blockIdx.y * 256;
  const int lane = tid & 63, wave = tid >> 6;
  const int quad = lane >> 4, lm = lane & 15;
  float4v acc[16] = {};
  const int ksteps = (Kdim + 31) >> 5;
  const int r = tid >> 2, c0 = (tid & 3) << 3;
  for (int ks = 0; ks < ksteps; ++ks) {
    const int k0 = ks << 5;
#pragma unroll
    for (int e = 0; e < 8; ++e) {
      int kk = k0 + c0 + e;
      float av = (m0 + r < rowsA && kk < Kdim) ? A[(m0 + r) * Kdim + kk] : 0.f;
      As[r][c0 + e] = __float2bfloat16(av);
    }
    {
      int n = n0 + tid;
      const float* __restrict__ wrow =
          (n < 1024) ? (wf + n * 450 + col_off) : (wb + (n - 1024) * 450 + col_off);
#pragma unroll
      for (int e2 = 0; e2 < 16; ++e2) {
        int kk = k0 + e2 * 2;
        float b0 = 0.f, b1 = 0.f;
        if (kk < Kdim) {  // Kdim even: pairs never straddle
          float2 v = *(const float2*)(wrow + kk);
          b0 = v.x;
          b1 = v.y;
        }
        Bs[tid][e2 * 2] = __float2bfloat16(b0);
        Bs[tid][e2 * 2 + 1] = __float2bfloat16(b1);
      }
    }
    __syncthreads();
    short8 af = *(const short8*)(&As[wave * 16 + lm][quad * 8]);
#pragma unroll
    for (int t = 0; t < 16; ++t) {
      short8 bf = *(const short8*)(&Bs[t * 16 + lm][quad * 8]);
      acc[t] = __builtin_amdgcn_mfma_f32_16x16x32_bf16(af, bf, acc[t], 0, 0, 0);
    }
    __syncthreads();
  }
#pragma unroll
  for (int t = 0; t < 16; ++t) {
#pragma unroll
    for (int rr = 0; rr < 4; ++rr) {
      int m = m0 + wave * 16 + quad * 4 + rr;
      int col = n0 + t * 16 + lm;
      if (m < rowsA) {
        float v = acc[t][rr];
        if (add_bias)
          v += (col < 1024) ? (bf1[col] + bf2[col]) : (bb1[col - 1024] + bb2[col - 1024]);
        int dir = col >> 10, r2 = col & 1023;
        int gate = r2 >> 8, u = r2 & 255;
        out[m * 2048 + dir * 1024 + u * 4 + gate] = __float2bfloat16(v);
      }
    }
  }
}

// ---------------------------------------------------------------------------
// Kernel B: BiLSTM recurrence, int8 dot4 + quad-split-K.
// 256 WGs (1 chain/CU), 512 thr. quad q owns units 2q,2q+1 (8 gate rows);
// thread (q,e) holds int8 W slice rows x K[64e,64e+64) = 128 VGPRs.
// Per step: 4 ds_read_b128 (h i8 slice) + 128 v_dot4 + DPP quad reduce.
// ---------------------------------------------------------------------------
__global__ __launch_bounds__(512, 1) void lstm_kernel(
    const float* __restrict__ whh_f, const float* __restrict__ whh_b,
    const int* __restrict__ x, const int* __restrict__ ptags, const int* __restrict__ gtags,
    const char* __restrict__ char_proj, const char* __restrict__ pin_proj,
    const char* __restrict__ tag_proj, __hip_bfloat16* __restrict__ h_out) {
  __shared__ __align__(16) int4 sidx[512];                 // byte offsets per t
  __shared__ __align__(16) signed char hbuf[2][256];       // h int8, double-buffered

  const int tid = threadIdx.x;
  const int q = tid >> 2, e = tid & 3;
  const int chain = blockIdx.x;
  const int dir = chain >> 7;
  const int b = chain & 127;
  const float* __restrict__ whh = dir ? whh_b : whh_f;

  // stage index byte-offsets (row pitch = 2048 bf16 = 4096 B)
  sidx[tid] = make_int4(x[b * 512 + tid] * 4096, ptags[b * 512 + tid] * 4096,
                        gtags[b * 512 + tid] * 4096, 0);
  if (tid < 16) ((int4*)hbuf[0])[tid] = make_int4(0, 0, 0, 0);

  // ---- int8-quantize weight slices: 8 gate rows, K in [64e, 64e+64) ----
  unsigned int W[8][16];
  float sc[8];
#pragma unroll
  for (int gg = 0; gg < 8; ++gg) {
    const int gate = gg >> 1, unit = 2 * q + (gg & 1);
    const float* __restrict__ wr = whh + (gate * 256 + unit) * 256 + e * 64;
    float mx = 0.f;
#pragma unroll
    for (int k4 = 0; k4 < 16; ++k4) {
      float4 v = ((const float4*)wr)[k4];
      mx = fmaxf(mx, fmaxf(fmaxf(fabsf(v.x), fabsf(v.y)), fmaxf(fabsf(v.z), fabsf(v.w))));
    }
    mx = qmax_f<XOR1>(mx);
    mx = qmax_f<XOR2>(mx);  // full-row max across the 4 k-slices
    float inv = (mx > 0.f) ? __fdividef(127.f, mx) : 0.f;
    sc[gg] = (mx > 0.f) ? (mx / (127.f * 127.f)) : 0.f;  // combined w*h dequant scale
#pragma unroll
    for (int k4 = 0; k4 < 16; ++k4) {
      float4 v = ((const float4*)wr)[k4];
      int b0 = (int)rintf(v.x * inv), b1 = (int)rintf(v.y * inv);
      int b2 = (int)rintf(v.z * inv), b3 = (int)rintf(v.w * inv);
      W[gg][k4] = (unsigned int)((b0 & 0xff) | ((b1 & 0xff) << 8) | ((b2 & 0xff) << 16) |
                                 ((b3 & 0xff) << 24));
    }
  }
  __syncthreads();

  const int unit_me = 2 * q + e;  // valid for e<2
  const int pre_off = dir * 2048 + unit_me * 8;  // bytes within a table row
  float cst = 0.f;

  // prefetch step 0 pre-gates (lanes e<2)
  int t_cur = dir ? 511 : 0;
  uint2 pc = {}, pp = {}, pt = {};
  if (e < 2) {
    int4 ix = sidx[t_cur];
    pc = *(const uint2*)(char_proj + ix.x + pre_off);
    pp = *(const uint2*)(pin_proj + ix.y + pre_off);
    pt = *(const uint2*)(tag_proj + ix.z + pre_off);
  }

  for (int s = 0; s < 512; ++s) {
    const int t = t_cur;
    const uint2 cv = pc, pv = pp, gv = pt;
    const int tn = dir ? (t > 0 ? t - 1 : 0) : (t < 511 ? t + 1 : 511);
    t_cur = tn;

    // h slice (64 int8 = 4 x b128), same buffer parity as s
    const uint4* hv = (const uint4*)(&hbuf[s & 1][e * 64]);
    uint4 H0 = hv[0], H1 = hv[1], H2 = hv[2], H3 = hv[3];

    // prefetch next step's pre-gates
    if (e < 2) {
      int4 ix = sidx[tn];
      pc = *(const uint2*)(char_proj + ix.x + pre_off);
      pp = *(const uint2*)(pin_proj + ix.y + pre_off);
      pt = *(const uint2*)(tag_proj + ix.z + pre_off);
    }

    int acc[8];
#pragma unroll
    for (int gg = 0; gg < 8; ++gg) {
      int a = 0;
      a = DOT4(W[gg][0], H0.x, a);
      a = DOT4(W[gg][1], H0.y, a);
      a = DOT4(W[gg][2], H0.z, a);
      a = DOT4(W[gg][3], H0.w, a);
      a = DOT4(W[gg][4], H1.x, a);
      a = DOT4(W[gg][5], H1.y, a);
      a = DOT4(W[gg][6], H1.z, a);
      a = DOT4(W[gg][7], H1.w, a);
      a = DOT4(W[gg][8], H2.x, a);
      a = DOT4(W[gg][9], H2.y, a);
      a = DOT4(W[gg][10], H2.z, a);
      a = DOT4(W[gg][11], H2.w, a);
      a = DOT4(W[gg][12], H3.x, a);
      a = DOT4(W[gg][13], H3.y, a);
      a = DOT4(W[gg][14], H3.z, a);
      a = DOT4(W[gg][15], H3.w, a);
      acc[gg] = a;
    }
    // quad butterfly: all 4 lanes get full-row sums
#pragma unroll
    for (int gg = 0; gg < 8; ++gg) {
      int v = qadd_i<XOR1>(acc[gg]);
      acc[gg] = qadd_i<XOR2>(v);
    }

    if (e < 2) {
      // pre-gates: (i,f) in .x, (g,o) in .y of each table's uint2
      float pi = bflo(cv.x) + bflo(pv.x) + bflo(gv.x);
      float pf = bfhi(cv.x) + bfhi(pv.x) + bfhi(gv.x);
      float pg = bflo(cv.y) + bflo(pv.y) + bflo(gv.y);
      float po = bfhi(cv.y) + bfhi(pv.y) + bfhi(gv.y);
      float gi = pi + (float)acc[0 + e] * sc[0 + e];
      float gf = pf + (float)acc[2 + e] * sc[2 + e];
      float gg_ = pg + (float)acc[4 + e] * sc[4 + e];
      float go = po + (float)acc[6 + e] * sc[6 + e];
      cst = sigmoidf_(gf) * cst + sigmoidf_(gi) * tanhf_(gg_);
      float hval = sigmoidf_(go) * tanhf_(cst);
      int hq = (int)rintf(hval * 127.f);
      hbuf[(s + 1) & 1][unit_me] = (signed char)hq;
      h_out[((size_t)chain * 512 + t) * 256 + unit_me] = __float2bfloat16(hval);
    }
    __syncthreads();
  }
}

// ---------------------------------------------------------------------------
// Kernel C: emissions GEMM. em[b*512+t][k] = Hcat[n]·w_out[k] + b_out[k]
// ---------------------------------------------------------------------------
__global__ __launch_bounds__(256) void emis_kernel(
    const __hip_bfloat16* __restrict__ h_glob, const float* __restrict__ w_out,
    const float* __restrict__ b_out, float* __restrict__ em) {
  __shared__ __align__(16) __hip_bfloat16 As[64][40];
  __shared__ __align__(16) __hip_bfloat16 Bs[32][40];
  const int tid = threadIdx.x;
  const int n0 = blockIdx.x * 64;
  const int lane = tid & 63, wave = tid >> 6, quad = lane >> 4, lm = lane & 15;
  float4v acc[2] = {};
  const int r = tid >> 2, c0 = (tid & 3) << 3;
  const int rb = tid >> 3, cb = (tid & 7) << 2;
  for (int ks = 0; ks < 16; ++ks) {
    const int j0 = ks * 32;
    const int dirk = j0 >> 8, jin = j0 & 255;
    const int n = n0 + r, bb = n >> 9, tt = n & 511;
    const uint4* src =
        (const uint4*)(h_glob + ((size_t)(dirk * 128 + bb) * 512 + tt) * 256 + jin + c0);
    *(uint4*)(&As[r][c0]) = *src;
#pragma unroll
    for (int e = 0; e < 4; ++e) {
      float v = (rb < 20) ? w_out[rb * 512 + j0 + cb + e] : 0.f;
      Bs[rb][cb + e] = __float2bfloat16(v);
    }
    __syncthreads();
    short8 af = *(const short8*)(&As[wave * 16 + lm][quad * 8]);
#pragma unroll
    for (int t2 = 0; t2 < 2; ++t2) {
      short8 bf = *(const short8*)(&Bs[t2 * 16 + lm][quad * 8]);
      acc[t2] = __builtin_amdgcn_mfma_f32_16x16x32_bf16(af, bf, acc[t2], 0, 0, 0);
    }
    __syncthreads();
  }
#pragma unroll
  for (int t2 = 0; t2 < 2; ++t2) {
#pragma unroll
    for (int rr = 0; rr < 4; ++rr) {
      int col = t2 * 16 + lm;
      if (col < 20) {
        int n = n0 + wave * 16 + quad * 4 + rr;
        em[(size_t)n * 20 + col] = acc[t2][rr] + b_out[col];
      }
    }
  }
}

// ---------------------------------------------------------------------------
// Kernel D: CRF forward NLL. 1 wave per batch element.
// Gold score computed in parallel; alpha chain with depth-2 em prefetch and
// stale-P renorm (refresh every 16 steps; drift << fp32 exp range).
// ---------------------------------------------------------------------------
__global__ __launch_bounds__(64) void crf_kernel(
    const float* __restrict__ em, const int* __restrict__ y,
    const float* __restrict__ start_trans, const float* __restrict__ end_trans,
    const float* __restrict__ trans, float* __restrict__ partials) {
  const int b = blockIdx.x;
  const int lane = threadIdx.x;
  const int jj = lane < 20 ? lane : 19;
  const bool act = lane < 20;
  __shared__ float sea[2][64];
  const float* __restrict__ emb = em + (size_t)b * 512 * 20;
  const int* __restrict__ yb = y + b * 512;

  // ---- gold-path score, parallel over t ----
  float s_part = 0.f;
#pragma unroll
  for (int i = 0; i < 8; ++i) {
    int t = lane + 64 * i;
    int yc = yb[t];
    float v = emb[t * 20 + yc];
    v += (t == 0) ? start_trans[yc] : trans[yb[t - 1] * 20 + yc];
    s_part += v;
  }
#pragma unroll
  for (int k = 32; k >= 1; k >>= 1) s_part += __shfl_xor(s_part, k, 64);
  float score = s_part + end_trans[yb[511]];

  // ---- forward algorithm ----
  float ET[20];
#pragma unroll
  for (int i = 0; i < 20; ++i) ET[i] = __expf(trans[i * 20 + jj]);
  float alpha = act ? (start_trans[jj] + emb[jj]) : -1e30f;
  float P = alpha;
#pragma unroll
  for (int k = 32; k >= 1; k >>= 1) P = fmaxf(P, __shfl_xor(P, k, 64));

  float eC = emb[1 * 20 + jj];
  float eN = emb[2 * 20 + jj];
  for (int t = 1; t < 512; ++t) {
    if ((t & 15) == 0) {
      P = alpha;
#pragma unroll
      for (int k = 32; k >= 1; k >>= 1) P = fmaxf(P, __shfl_xor(P, k, 64));
    }
    sea[t & 1][lane] = __expf(alpha - P);
    int tf = t + 2 < 512 ? t + 2 : 511;
    float eF = emb[tf * 20 + jj];
    __syncthreads();
    float s0 = 0.f, s1 = 0.f;
#pragma unroll
    for (int i = 0; i < 20; i += 2) {
      s0 += sea[t & 1][i] * ET[i];
      s1 += sea[t & 1][i + 1] * ET[i + 1];
    }
    if (act) alpha = P + __logf(s0 + s1) + eC;
    eC = eN;
    eN = eF;
  }
  float v = act ? (alpha + end_trans[jj]) : -1e30f;
  float Pz = v;
#pragma unroll
  for (int k = 32; k >= 1; k >>= 1) Pz = fmaxf(Pz, __shfl_xor(Pz, k, 64));
  float e2 = __expf(v - Pz);
#pragma unroll
  for (int k = 32; k >= 1; k >>= 1) e2 += __shfl_xor(e2, k, 64);
  float logZ = Pz + __logf(e2);
  if (lane == 0) partials[b] = logZ - score;
}

__global__ __launch_bounds__(128) void reduce_kernel(const float* __restrict__ partials,
                                                     float* __restrict__ out) {
  const int tid = threadIdx.x;
  float v = partials[tid];
#pragma unroll
  for (int k = 32; k >= 1; k >>= 1) v += __shfl_xor(v, k, 64);
  __shared__ float tmp[2];
  if ((tid & 63) == 0) tmp[tid >> 6] = v;
  __syncthreads();
  if (tid == 0) out[0] = tmp[0] + tmp[1];
}

// ---------------------------------------------------------------------------
extern "C" void kernel_launch(void* const* d_in, const int* in_sizes, int n_in,
                              void* d_out, int out_size, void* d_ws, size_t ws_size,
                              hipStream_t stream) {
  const int* x = (const int*)d_in[0];
  const int* y = (const int*)d_in[1];
  const int* pre_tags = (const int*)d_in[2];
  const int* pinyin_tags = (const int*)d_in[3];
  const float* char_emb = (const float*)d_in[5];
  const float* tag_emb = (const float*)d_in[6];
  const float* pinyin_emb = (const float*)d_in[7];
  const float* w_ih_f = (const float*)d_in[8];
  const float* w_hh_f = (const float*)d_in[9];
  const float* b_ih_f = (const float*)d_in[10];
  const float* b_hh_f = (const float*)d_in[11];
  const float* w_ih_b = (const float*)d_in[12];
  const float* w_hh_b = (const float*)d_in[13];
  const float* b_ih_b = (const float*)d_in[14];
  const float* b_hh_b = (const float*)d_in[15];
  const float* w_out = (const float*)d_in[16];
  const float* b_out = (const float*)d_in[17];
  const float* start_trans = (const float*)d_in[18];
  const float* end_trans = (const float*)d_in[19];
  const float* trans = (const float*)d_in[20];

  char* ws = (char*)d_ws;
  __hip_bfloat16* char_proj = (__hip_bfloat16*)(ws);            // 10002*2048*2 = 40968192
  __hip_bfloat16* pin_proj = (__hip_bfloat16*)(ws + 40968192);  // 500*2048*2  = 2048000
  __hip_bfloat16* tag_proj = (__hip_bfloat16*)(ws + 43016192);  // 20*2048*2   = 81920
  __hip_bfloat16* h_glob = (__hip_bfloat16*)(ws + 43098112);    // 2*128*512*256*2 = 67108864
  float* em = (float*)(ws + 110206976);                         // 65536*20*4 = 5242880
  float* partials = (float*)(ws + 115449856);                   // 128*4

  proj_gemm<<<dim3(157, 8), 256, 0, stream>>>(char_emb, 10002, 300, 0, w_ih_f, w_ih_b,
                                              nullptr, nullptr, nullptr, nullptr, char_proj, 0);
  proj_gemm<<<dim3(8, 8), 256, 0, stream>>>(pinyin_emb, 500, 100, 300, w_ih_f, w_ih_b,
                                            nullptr, nullptr, nullptr, nullptr, pin_proj, 0);
  proj_gemm<<<dim3(1, 8), 256, 0, stream>>>(tag_emb, 20, 50, 400, w_ih_f, w_ih_b,
                                            b_ih_f, b_hh_f, b_ih_b, b_hh_b, tag_proj, 1);

  lstm_kernel<<<256, 512, 0, stream>>>(w_hh_f, w_hh_b, x, pinyin_tags, pre_tags,
                                       (const char*)char_proj, (const char*)pin_proj,
                                       (const char*)tag_proj, h_glob);

  emis_kernel<<<1024, 256, 0, stream>>>(h_glob, w_out, b_out, em);
  crf_kernel<<<128, 64, 0, stream>>>(em, y, start_trans, end_trans, trans, partials);
  reduce_kernel<<<1, 128, 0, stream>>>(partials, (float*)d_out);
}